// Round 4
// baseline (240.363 us; speedup 1.0000x reference)
//
#include <hip/hip_runtime.h>

#define BH (512*2048)
#define PPLANE (512ull*8192ull)          // elems per partial plane [512][8192]
#define PLANE_BYTES (PPLANE*2ull)        // bf16

typedef __attribute__((ext_vector_type(8))) short short8;
typedef __attribute__((ext_vector_type(4))) float floatx4;
typedef __attribute__((ext_vector_type(4))) unsigned int uint4v;
typedef __attribute__((ext_vector_type(8))) unsigned short ushort8v;

// pack two f32 -> two bf16 (round-half-up) in one dword: 3 VALU ops
__device__ inline unsigned pk2(float a, float b){
    unsigned ua = __builtin_bit_cast(unsigned, a) + 0x8000u;
    unsigned ub = __builtin_bit_cast(unsigned, b) + 0x8000u;
    return __builtin_amdgcn_perm(ub, ua, 0x07060302u);   // [ub.hi16 | ua.hi16]
}
__device__ inline unsigned short f2bf1(float x){
    return (unsigned short)((__builtin_bit_cast(unsigned, x) + 0x8000u) >> 16);
}
__device__ inline float bf2f(unsigned short s){
    return __builtin_bit_cast(float, ((unsigned)s) << 16);
}
// 16B-granule XOR swizzle (R3-verified: 0 bank conflicts)
__device__ inline int swz(int r, int g){ return r*4 + (g ^ ((r>>1)&3)); }

__device__ inline float fsig(float x){ return __builtin_amdgcn_rcpf(1.f + __expf(-x)); }
__device__ inline float ftanh(float x){ return 2.f*fsig(2.f*x) - 1.f; }

// One K-slice of the gate GEMM. Block tile 128x128, 4 waves of 64x64 (4x4 MFMA
// 16x16x32), BK=32, double-buffered LDS, DEPTH-2 register prefetch so the
// cvt-stage waitcnt is vmcnt(~20) not vmcnt(0) (loads land a full iter early).
__global__ __launch_bounds__(256, 2) void gemm_tile(
    const float* __restrict__ inputs, const float* __restrict__ states,
    const float* __restrict__ Wi, const float* __restrict__ Ui,
    const float* __restrict__ Wf, const float* __restrict__ Uf,
    const float* __restrict__ Wg, const float* __restrict__ Ug,
    const float* __restrict__ Wc, const float* __restrict__ Uc,
    unsigned short* __restrict__ P, int KB)
{
    __shared__ uint4v As[2][512];   // 128 rows x 4 k-octet granules, swizzled
    __shared__ uint4v Bs[2][512];

    const int t    = threadIdx.x;
    const int m0   = blockIdx.y * 128;
    const int z    = blockIdx.z;
    const int nblk = blockIdx.x;
    const int gate = nblk >> 4;
    const int c0   = (nblk & 15) * 128;
    const int gk   = z * KB;

    const float* Abase; const float* Bsel; int ko;
    if (gk < 2048) {
        Abase = inputs; ko = gk;
        switch (gate){ case 0: Bsel=Wi; break; case 1: Bsel=Wf; break;
                       case 2: Bsel=Wg; break; default: Bsel=Wc; }
    } else {
        Abase = states; ko = gk - 2048;     // states[0] = prevstate
        switch (gate){ case 0: Bsel=Ui; break; case 1: Bsel=Uf; break;
                       case 2: Bsel=Ug; break; default: Bsel=Uc; }
    }
    const int NIT = KB >> 5;                 // even (16 or 32 or 64)

    const int lane  = t & 63;
    const int wave  = t >> 6;
    const int wm    = (wave & 1) * 64;
    const int wn    = (wave >> 1) * 64;
    const int row16 = lane & 15;
    const int g4    = lane >> 4;

    // staging assignments
    const int ar  = t >> 2;                 // A rows ar, ar+64; k-octet ag
    const int ag  = t & 3;
    const int bn  = t & 127;                // B col bn; k-octets bg2, bg2+1
    const int bg2 = (t >> 7) * 2;

    const float* Ap  = Abase + (size_t)(m0 + ar) * 2048 + ko + ag * 8;
    const float* Bpt = Bsel  + ((size_t)ko + bg2 * 8) * 2048 + c0 + bn;

    floatx4 acc[4][4];
    #pragma unroll
    for (int i = 0; i < 4; i++)
        #pragma unroll
        for (int j = 0; j < 4; j++)
            acc[i][j] = (floatx4){0.f,0.f,0.f,0.f};

    // two register stages
    floatx4 xa0,xa1,xa2,xa3; float xb0[8], xb1[8];   // stage X
    floatx4 ya0,ya1,ya2,ya3; float yb0[8], yb1[8];   // stage Y

    auto LOADX = [&](int k){
        const float* ap = Ap + k * 32;
        xa0 = *(const floatx4*)ap;             xa1 = *(const floatx4*)(ap + 4);
        xa2 = *(const floatx4*)(ap + 64*2048); xa3 = *(const floatx4*)(ap + 64*2048 + 4);
        const float* bp = Bpt + (size_t)k * 32 * 2048;
        #pragma unroll
        for (int j = 0; j < 8; j++) xb0[j] = bp[(size_t)j * 2048];
        #pragma unroll
        for (int j = 0; j < 8; j++) xb1[j] = bp[(size_t)(8 + j) * 2048];
    };
    auto LOADY = [&](int k){
        const float* ap = Ap + k * 32;
        ya0 = *(const floatx4*)ap;             ya1 = *(const floatx4*)(ap + 4);
        ya2 = *(const floatx4*)(ap + 64*2048); ya3 = *(const floatx4*)(ap + 64*2048 + 4);
        const float* bp = Bpt + (size_t)k * 32 * 2048;
        #pragma unroll
        for (int j = 0; j < 8; j++) yb0[j] = bp[(size_t)j * 2048];
        #pragma unroll
        for (int j = 0; j < 8; j++) yb1[j] = bp[(size_t)(8 + j) * 2048];
    };
    auto CVTX = [&](int buf){
        uint4v w;
        w.x=pk2(xa0[0],xa0[1]); w.y=pk2(xa0[2],xa0[3]); w.z=pk2(xa1[0],xa1[1]); w.w=pk2(xa1[2],xa1[3]);
        As[buf][swz(ar, ag)] = w;
        w.x=pk2(xa2[0],xa2[1]); w.y=pk2(xa2[2],xa2[3]); w.z=pk2(xa3[0],xa3[1]); w.w=pk2(xa3[2],xa3[3]);
        As[buf][swz(ar+64, ag)] = w;
        w.x=pk2(xb0[0],xb0[1]); w.y=pk2(xb0[2],xb0[3]); w.z=pk2(xb0[4],xb0[5]); w.w=pk2(xb0[6],xb0[7]);
        Bs[buf][swz(bn, bg2)] = w;
        w.x=pk2(xb1[0],xb1[1]); w.y=pk2(xb1[2],xb1[3]); w.z=pk2(xb1[4],xb1[5]); w.w=pk2(xb1[6],xb1[7]);
        Bs[buf][swz(bn, bg2+1)] = w;
    };
    auto CVTY = [&](int buf){
        uint4v w;
        w.x=pk2(ya0[0],ya0[1]); w.y=pk2(ya0[2],ya0[3]); w.z=pk2(ya1[0],ya1[1]); w.w=pk2(ya1[2],ya1[3]);
        As[buf][swz(ar, ag)] = w;
        w.x=pk2(ya2[0],ya2[1]); w.y=pk2(ya2[2],ya2[3]); w.z=pk2(ya3[0],ya3[1]); w.w=pk2(ya3[2],ya3[3]);
        As[buf][swz(ar+64, ag)] = w;
        w.x=pk2(yb0[0],yb0[1]); w.y=pk2(yb0[2],yb0[3]); w.z=pk2(yb0[4],yb0[5]); w.w=pk2(yb0[6],yb0[7]);
        Bs[buf][swz(bn, bg2)] = w;
        w.x=pk2(yb1[0],yb1[1]); w.y=pk2(yb1[2],yb1[3]); w.z=pk2(yb1[4],yb1[5]); w.w=pk2(yb1[6],yb1[7]);
        Bs[buf][swz(bn, bg2+1)] = w;
    };
    auto MFMAS = [&](int buf){
        short8 afr[4], bfr[4];
        #pragma unroll
        for (int mi = 0; mi < 4; mi++)
            afr[mi] = *(const short8*)&As[buf][swz(wm + mi*16 + row16, g4)];
        #pragma unroll
        for (int ni = 0; ni < 4; ni++)
            bfr[ni] = *(const short8*)&Bs[buf][swz(wn + ni*16 + row16, g4)];
        #pragma unroll
        for (int mi = 0; mi < 4; mi++)
            #pragma unroll
            for (int ni = 0; ni < 4; ni++)
                acc[mi][ni] = __builtin_amdgcn_mfma_f32_16x16x32_bf16(
                    afr[mi], bfr[ni], acc[mi][ni], 0, 0, 0);
    };

    // prologue: buf0 <- tile0 (via X); Y <- tile1
    LOADX(0);
    CVTX(0);
    LOADY(1);

    // steady state, parity hardcoded:
    // even kk: buf0 has tile kk, Y has tile kk+1; load kk+2->X, mfma buf0, cvt Y->buf1
    // odd  kk: buf1 has tile kk, X has tile kk+1; load kk+2->Y, mfma buf1, cvt X->buf0
    for (int kk = 0; kk < NIT; kk += 2) {
        __syncthreads();
        if (kk + 2 < NIT) LOADX(kk + 2);
        MFMAS(0);
        CVTY(1);                       // tile kk+1 (loaded one full iter ago)

        __syncthreads();
        if (kk + 3 < NIT) LOADY(kk + 3);
        MFMAS(1);
        if (kk + 2 < NIT) CVTX(0);     // tile kk+2
    }

    // epilogue: C/D layout col=lane&15, row=(lane>>4)*4+reg (m89-verified)
    unsigned short* dst = P + (size_t)z * PPLANE;
    const int gbase = gate * 2048 + c0;
    #pragma unroll
    for (int mi = 0; mi < 4; mi++)
        #pragma unroll
        for (int ni = 0; ni < 4; ni++)
            #pragma unroll
            for (int j = 0; j < 4; j++) {
                int row = m0 + wm + mi*16 + g4*4 + j;
                int col = gbase + wn + ni*16 + row16;
                dst[(size_t)row * 8192 + col] = f2bf1(acc[mi][ni][j]);
            }
}

// activations + LSTM combine; sums nz bf16 partial planes, writes fp32 outputs
__global__ __launch_bounds__(256) void combine_kernel(
    float* __restrict__ out, const unsigned short* __restrict__ P,
    const float* __restrict__ states,
    const float* __restrict__ bi, const float* __restrict__ bfv,
    const float* __restrict__ bg, const float* __restrict__ bc, int nz)
{
    const int idx = (blockIdx.x * 256 + threadIdx.x) * 8;
    const int row = idx >> 11;
    const int h   = idx & 2047;
    const size_t base = (size_t)row * 8192 + h;

    float xi[8], xf[8], xg[8], xc[8];
    #pragma unroll
    for (int e = 0; e < 8; e++) {
        xi[e] = bi[h+e]; xf[e] = bfv[h+e]; xg[e] = bg[h+e]; xc[e] = bc[h+e];
    }
    for (int z = 0; z < nz; z++) {
        const unsigned short* Pz = P + (size_t)z * PPLANE;
        ushort8v vi = *(const ushort8v*)&Pz[base];
        ushort8v vf = *(const ushort8v*)&Pz[base + 2048];
        ushort8v vg = *(const ushort8v*)&Pz[base + 4096];
        ushort8v vc = *(const ushort8v*)&Pz[base + 6144];
        #pragma unroll
        for (int e = 0; e < 8; e++) {
            xi[e] += bf2f(vi[e]); xf[e] += bf2f(vf[e]);
            xg[e] += bf2f(vg[e]); xc[e] += bf2f(vc[e]);
        }
    }

    const float* po = states + BH;       // states[1] = prevoutput
    floatx4 pov[2];
    pov[0] = *(const floatx4*)&po[idx];
    pov[1] = *(const floatx4*)&po[idx + 4];

    floatx4 vcv[2], vsv[2];
    #pragma unroll
    for (int q = 0; q < 2; q++)
        #pragma unroll
        for (int j = 0; j < 4; j++) {
            int e = q*4 + j;
            float c = fsig(xf[e]) * pov[q][j] + fsig(xi[e]) * ftanh(xc[e]);
            vcv[q][j] = c;
            vsv[q][j] = fsig(xg[e]) * ftanh(c);
        }
    #pragma unroll
    for (int q = 0; q < 2; q++) {
        *(floatx4*)&out[idx + q*4]          = vcv[q];   // c
        *(floatx4*)&out[BH + idx + q*4]     = vsv[q];   // state
        *(floatx4*)&out[2*BH + idx + q*4]   = vcv[q];   // c
    }
}

extern "C" void kernel_launch(void* const* d_in, const int* in_sizes, int n_in,
                              void* d_out, int out_size, void* d_ws, size_t ws_size,
                              hipStream_t stream) {
    const float* inputs = (const float*)d_in[0];
    const float* states = (const float*)d_in[1];
    const float* Wi = (const float*)d_in[2];
    const float* Ui = (const float*)d_in[3];
    const float* bi = (const float*)d_in[4];
    const float* Wf = (const float*)d_in[5];
    const float* Uf = (const float*)d_in[6];
    const float* bf = (const float*)d_in[7];
    const float* Wg = (const float*)d_in[8];
    const float* Ug = (const float*)d_in[9];
    const float* bg = (const float*)d_in[10];
    const float* Wc = (const float*)d_in[11];
    const float* Uc = (const float*)d_in[12];
    const float* bc = (const float*)d_in[13];
    float* out = (float*)d_out;
    unsigned short* P = (unsigned short*)d_ws;

    const int nz = (ws_size >= 4 * PLANE_BYTES) ? 4 : 2;
    const int KB = 4096 / nz;

    dim3 grid(64, 4, nz);
    gemm_tile<<<grid, 256, 0, stream>>>(inputs, states, Wi, Ui, Wf, Uf,
                                        Wg, Ug, Wc, Uc, P, KB);
    combine_kernel<<<BH / (8 * 256), 256, 0, stream>>>(out, P, states,
                                                       bi, bf, bg, bc, nz);
}

// Round 5
// 232.033 us; speedup vs baseline: 1.0359x; 1.0359x over previous
//
#include <hip/hip_runtime.h>

#define BH (512*2048)
#define BHA 1048576ull                   // 512*2048 elems (one activation plane)
#define PPLANE (512ull*8192ull)          // elems per partial plane [512][8192]
#define PLANE_BYTES (PPLANE*2ull)        // bf16
#define WT_ELEMS (8ull*2048*2048)        // transposed bf16 weights (8 matrices)
#define AB_ELEMS (2ull*512*2048)         // bf16 activations (inputs + prevstate)
#define LDT 40

typedef __attribute__((ext_vector_type(8))) short short8;
typedef __attribute__((ext_vector_type(4))) float floatx4;
typedef __attribute__((ext_vector_type(4))) unsigned int uint4v;
typedef __attribute__((ext_vector_type(8))) unsigned short ushort8v;

#define GLOAD_LDS16(g, l) __builtin_amdgcn_global_load_lds( \
    (const __attribute__((address_space(1))) unsigned int*)(g), \
    (__attribute__((address_space(3))) unsigned int*)(l), 16, 0, 0)

// pack two f32 -> two bf16 (round-half-up) in one dword (R2-R4 verified)
__device__ inline unsigned pk2(float a, float b){
    unsigned ua = __builtin_bit_cast(unsigned, a) + 0x8000u;
    unsigned ub = __builtin_bit_cast(unsigned, b) + 0x8000u;
    return __builtin_amdgcn_perm(ub, ua, 0x07060302u);
}
__device__ inline unsigned short f2bf1(float x){
    return (unsigned short)((__builtin_bit_cast(unsigned, x) + 0x8000u) >> 16);
}
__device__ inline float bf2f(unsigned short s){
    return __builtin_bit_cast(float, ((unsigned)s) << 16);
}
__device__ inline int swz(int r, int g){ return r*4 + (g ^ ((r>>1)&3)); }
__device__ inline float fsig(float x){ return __builtin_amdgcn_rcpf(1.f + __expf(-x)); }
__device__ inline float ftanh(float x){ return 2.f*fsig(2.f*x) - 1.f; }

// ---------------------------------------------------------------------------
// Prepass: bid<8192 -> one 32k x 128n weight tile, transposed+cast to bf16,
// stored as [n_loc 0..127][k_loc 0..31] contiguous 8KB; tile index
// ((gate*16+nb)*128 + kt). kt<64 = W rows kt*32.., kt>=64 = U rows (kt-64)*32..
// bid>=8192 -> cast inputs (plane 0) / states[0] (plane 1) to bf16 flat.
// ---------------------------------------------------------------------------
__global__ __launch_bounds__(256) void prep(
    const float* __restrict__ inputs, const float* __restrict__ states,
    const float* __restrict__ Wi, const float* __restrict__ Ui,
    const float* __restrict__ Wf, const float* __restrict__ Uf,
    const float* __restrict__ Wg, const float* __restrict__ Ug,
    const float* __restrict__ Wc, const float* __restrict__ Uc,
    unsigned short* __restrict__ Wt, unsigned short* __restrict__ Ab)
{
    const int bid = blockIdx.x, tid = threadIdx.x;
    if (bid < 8192) {
        const int gate = bid >> 11, r = bid & 2047, nb = r >> 7, kt = r & 127;
        const float* src; int krow;
        if (kt < 64) {
            krow = kt * 32;
            switch (gate){ case 0: src=Wi; break; case 1: src=Wf; break;
                           case 2: src=Wg; break; default: src=Wc; }
        } else {
            krow = (kt - 64) * 32;
            switch (gate){ case 0: src=Ui; break; case 1: src=Uf; break;
                           case 2: src=Ug; break; default: src=Uc; }
        }
        const int n_loc = tid >> 1, k_loc = (tid & 1) * 16;
        const float* sp = src + (size_t)(krow + k_loc) * 2048 + nb * 128 + n_loc;
        unsigned o[8];
        #pragma unroll
        for (int j = 0; j < 8; j++) {
            float f0 = sp[(size_t)(2*j)   * 2048];
            float f1 = sp[(size_t)(2*j+1) * 2048];
            o[j] = pk2(f0, f1);
        }
        unsigned short* op = Wt + (size_t)bid * 4096 + n_loc * 32 + k_loc;
        *(uint4v*)op       = (uint4v){o[0],o[1],o[2],o[3]};
        *(uint4v*)(op + 8) = (uint4v){o[4],o[5],o[6],o[7]};
    } else {
        const size_t off = ((size_t)(bid - 8192) * 256 + tid) * 8;
        const float* src = (off < BHA) ? (inputs + off) : (states + (off - BHA));
        floatx4 v0 = *(const floatx4*)src;
        floatx4 v1 = *(const floatx4*)(src + 4);
        uint4v w;
        w.x = pk2(v0[0],v0[1]); w.y = pk2(v0[2],v0[3]);
        w.z = pk2(v1[0],v1[1]); w.w = pk2(v1[2],v1[3]);
        *(uint4v*)(Ab + off) = w;
    }
}

// ---------------------------------------------------------------------------
// Main GEMM (bf16 pre-converted inputs): m97-style K-loop.
// Block 128x128, 4 waves of 64x64 (4x4 x mfma_16x16x32_bf16), BK=32,
// double-buffered LDS filled by global_load_lds width-16, one barrier/iter.
// ---------------------------------------------------------------------------
__global__ __launch_bounds__(256, 4) void gemm_lds(
    const unsigned short* __restrict__ Wt, const unsigned short* __restrict__ Ab,
    unsigned short* __restrict__ P)
{
    __shared__ unsigned short As[2][4096];   // [m 0..127][k 0..31]
    __shared__ unsigned short Bs[2][4096];   // [n 0..127][k 0..31]

    const int t = threadIdx.x, lane = t & 63, wave = t >> 6;
    const int nblk = blockIdx.x, gate = nblk >> 4, nb = nblk & 15;
    const int m0 = blockIdx.y * 128, z = blockIdx.z;

    const unsigned short* Bt = Wt + ((size_t)(gate*16 + nb) * 128 + z*32) * 4096;
    const unsigned short* Abase = Ab + (size_t)(z >> 1) * BHA
                                     + (size_t)m0 * 2048 + (z & 1) * 1024;

    const int i0 = wave * 2, i1 = wave * 2 + 1;   // this wave's two DMA slots
    const unsigned short* ag0 = Abase + (size_t)(i0*16 + (lane>>2)) * 2048 + (lane&3)*8;
    const unsigned short* ag1 = Abase + (size_t)(i1*16 + (lane>>2)) * 2048 + (lane&3)*8;
    const unsigned short* bg0 = Bt + i0*512 + lane*8;
    const unsigned short* bg1 = Bt + i1*512 + lane*8;

    floatx4 acc[4][4];
    #pragma unroll
    for (int i = 0; i < 4; i++)
        #pragma unroll
        for (int j = 0; j < 4; j++)
            acc[i][j] = (floatx4){0.f,0.f,0.f,0.f};

    const int wm = (wave & 1) * 64, wn = (wave >> 1) * 64;
    const int row16 = lane & 15, g4 = lane >> 4;

    // prologue: DMA tile 0 into buf 0
    GLOAD_LDS16(ag0, &As[0][i0*512]);
    GLOAD_LDS16(ag1, &As[0][i1*512]);
    GLOAD_LDS16(bg0, &Bs[0][i0*512]);
    GLOAD_LDS16(bg1, &Bs[0][i1*512]);
    __syncthreads();

    for (int kk = 0; kk < 32; kk++) {
        const int cur = kk & 1;
        if (kk < 31) {                       // DMA next tile into other buffer
            const int nxt = cur ^ 1;
            GLOAD_LDS16(ag0 + (kk+1)*32,   &As[nxt][i0*512]);
            GLOAD_LDS16(ag1 + (kk+1)*32,   &As[nxt][i1*512]);
            GLOAD_LDS16(bg0 + (kk+1)*4096, &Bs[nxt][i0*512]);
            GLOAD_LDS16(bg1 + (kk+1)*4096, &Bs[nxt][i1*512]);
        }
        short8 afr[4], bfr[4];
        #pragma unroll
        for (int mi = 0; mi < 4; mi++)
            afr[mi] = *(const short8*)&As[cur][(wm + mi*16 + row16)*32 + g4*8];
        #pragma unroll
        for (int ni = 0; ni < 4; ni++)
            bfr[ni] = *(const short8*)&Bs[cur][(wn + ni*16 + row16)*32 + g4*8];
        #pragma unroll
        for (int mi = 0; mi < 4; mi++)
            #pragma unroll
            for (int ni = 0; ni < 4; ni++)
                acc[mi][ni] = __builtin_amdgcn_mfma_f32_16x16x32_bf16(
                    afr[mi], bfr[ni], acc[mi][ni], 0, 0, 0);
        __syncthreads();                     // drains DMA (vmcnt) + barrier
    }

    unsigned short* dst = P + (size_t)z * PPLANE;
    const int gbase = gate * 2048 + nb * 128;
    #pragma unroll
    for (int mi = 0; mi < 4; mi++)
        #pragma unroll
        for (int ni = 0; ni < 4; ni++)
            #pragma unroll
            for (int j = 0; j < 4; j++) {
                int row = m0 + wm + mi*16 + g4*4 + j;
                int col = gbase + wn + ni*16 + row16;
                dst[(size_t)row * 8192 + col] = f2bf1(acc[mi][ni][j]);
            }
}

// ---------------------------------------------------------------------------
// Fallback GEMM (R3 version, fused fp32 staging) for small ws_size.
// ---------------------------------------------------------------------------
__global__ __launch_bounds__(256, 2) void gemm_tile(
    const float* __restrict__ inputs, const float* __restrict__ states,
    const float* __restrict__ Wi, const float* __restrict__ Ui,
    const float* __restrict__ Wf, const float* __restrict__ Uf,
    const float* __restrict__ Wg, const float* __restrict__ Ug,
    const float* __restrict__ Wc, const float* __restrict__ Uc,
    unsigned short* __restrict__ P, int KB)
{
    __shared__ uint4v As[2][512];
    __shared__ uint4v Bs[2][512];

    const int t = threadIdx.x;
    const int m0 = blockIdx.y * 128;
    const int z = blockIdx.z;
    const int nblk = blockIdx.x;
    const int gate = nblk >> 4;
    const int c0 = (nblk & 15) * 128;
    const int gk = z * KB;

    const float* Abase; const float* Bsel; int ko;
    if (gk < 2048) {
        Abase = inputs; ko = gk;
        switch (gate){ case 0: Bsel=Wi; break; case 1: Bsel=Wf; break;
                       case 2: Bsel=Wg; break; default: Bsel=Wc; }
    } else {
        Abase = states; ko = gk - 2048;
        switch (gate){ case 0: Bsel=Ui; break; case 1: Bsel=Uf; break;
                       case 2: Bsel=Ug; break; default: Bsel=Uc; }
    }
    const int NIT = KB >> 5;

    const int lane = t & 63, wave = t >> 6;
    const int wm = (wave & 1) * 64, wn = (wave >> 1) * 64;
    const int row16 = lane & 15, g4 = lane >> 4;
    const int ar = t >> 2, ag = t & 3;
    const int bn = t & 127, bg2 = (t >> 7) * 2;

    const float* Ap = Abase + (size_t)(m0 + ar) * 2048 + ko + ag * 8;
    const float* Bp = Bsel + (size_t)ko * 2048 + c0 + bn;

    floatx4 acc[4][4];
    #pragma unroll
    for (int i = 0; i < 4; i++)
        #pragma unroll
        for (int j = 0; j < 4; j++)
            acc[i][j] = (floatx4){0.f,0.f,0.f,0.f};

    floatx4 a0,a1,a2,a3; float b0[8], b1[8];
    a0 = *(const floatx4*)Ap;             a1 = *(const floatx4*)(Ap + 4);
    a2 = *(const floatx4*)(Ap + 64*2048); a3 = *(const floatx4*)(Ap + 64*2048 + 4);
    #pragma unroll
    for (int j = 0; j < 8; j++) b0[j] = Bp[(size_t)(bg2*8 + j) * 2048];
    #pragma unroll
    for (int j = 0; j < 8; j++) b1[j] = Bp[(size_t)(bg2*8 + 8 + j) * 2048];
    {
        uint4v w;
        w.x=pk2(a0[0],a0[1]); w.y=pk2(a0[2],a0[3]); w.z=pk2(a1[0],a1[1]); w.w=pk2(a1[2],a1[3]);
        As[0][swz(ar, ag)] = w;
        w.x=pk2(a2[0],a2[1]); w.y=pk2(a2[2],a2[3]); w.z=pk2(a3[0],a3[1]); w.w=pk2(a3[2],a3[3]);
        As[0][swz(ar+64, ag)] = w;
        w.x=pk2(b0[0],b0[1]); w.y=pk2(b0[2],b0[3]); w.z=pk2(b0[4],b0[5]); w.w=pk2(b0[6],b0[7]);
        Bs[0][swz(bn, bg2)] = w;
        w.x=pk2(b1[0],b1[1]); w.y=pk2(b1[2],b1[3]); w.z=pk2(b1[4],b1[5]); w.w=pk2(b1[6],b1[7]);
        Bs[0][swz(bn, bg2+1)] = w;
    }

    for (int kk = 0; kk < NIT; kk++) {
        __syncthreads();
        const int cur = kk & 1;
        if (kk + 1 < NIT) {
            const float* ap = Ap + (kk+1) * 32;
            a0 = *(const floatx4*)ap;             a1 = *(const floatx4*)(ap + 4);
            a2 = *(const floatx4*)(ap + 64*2048); a3 = *(const floatx4*)(ap + 64*2048 + 4);
            const float* bp = Bp + (size_t)(kk+1) * 32 * 2048;
            #pragma unroll
            for (int j = 0; j < 8; j++) b0[j] = bp[(size_t)(bg2*8 + j) * 2048];
            #pragma unroll
            for (int j = 0; j < 8; j++) b1[j] = bp[(size_t)(bg2*8 + 8 + j) * 2048];
        }
        short8 afr[4], bfr[4];
        #pragma unroll
        for (int mi = 0; mi < 4; mi++)
            afr[mi] = *(const short8*)&As[cur][swz(wm + mi*16 + row16, g4)];
        #pragma unroll
        for (int ni = 0; ni < 4; ni++)
            bfr[ni] = *(const short8*)&Bs[cur][swz(wn + ni*16 + row16, g4)];
        #pragma unroll
        for (int mi = 0; mi < 4; mi++)
            #pragma unroll
            for (int ni = 0; ni < 4; ni++)
                acc[mi][ni] = __builtin_amdgcn_mfma_f32_16x16x32_bf16(
                    afr[mi], bfr[ni], acc[mi][ni], 0, 0, 0);
        if (kk + 1 < NIT) {
            const int nxt = cur ^ 1;
            uint4v w;
            w.x=pk2(a0[0],a0[1]); w.y=pk2(a0[2],a0[3]); w.z=pk2(a1[0],a1[1]); w.w=pk2(a1[2],a1[3]);
            As[nxt][swz(ar, ag)] = w;
            w.x=pk2(a2[0],a2[1]); w.y=pk2(a2[2],a2[3]); w.z=pk2(a3[0],a3[1]); w.w=pk2(a3[2],a3[3]);
            As[nxt][swz(ar+64, ag)] = w;
            w.x=pk2(b0[0],b0[1]); w.y=pk2(b0[2],b0[3]); w.z=pk2(b0[4],b0[5]); w.w=pk2(b0[6],b0[7]);
            Bs[nxt][swz(bn, bg2)] = w;
            w.x=pk2(b1[0],b1[1]); w.y=pk2(b1[2],b1[3]); w.z=pk2(b1[4],b1[5]); w.w=pk2(b1[6],b1[7]);
            Bs[nxt][swz(bn, bg2+1)] = w;
        }
    }

    unsigned short* dst = P + (size_t)z * PPLANE;
    const int gbase = gate * 2048 + c0;
    #pragma unroll
    for (int mi = 0; mi < 4; mi++)
        #pragma unroll
        for (int ni = 0; ni < 4; ni++)
            #pragma unroll
            for (int j = 0; j < 4; j++) {
                int row = m0 + wm + mi*16 + g4*4 + j;
                int col = gbase + wn + ni*16 + row16;
                dst[(size_t)row * 8192 + col] = f2bf1(acc[mi][ni][j]);
            }
}

// activations + LSTM combine
__global__ __launch_bounds__(256) void combine_kernel(
    float* __restrict__ out, const unsigned short* __restrict__ P,
    const float* __restrict__ states,
    const float* __restrict__ bi, const float* __restrict__ bfv,
    const float* __restrict__ bg, const float* __restrict__ bc, int nz)
{
    const int idx = (blockIdx.x * 256 + threadIdx.x) * 8;
    const int row = idx >> 11;
    const int h = idx & 2047;
    const size_t base = (size_t)row * 8192 + h;

    float xi[8], xf[8], xg[8], xc[8];
    #pragma unroll
    for (int e = 0; e < 8; e++) {
        xi[e] = bi[h+e]; xf[e] = bfv[h+e]; xg[e] = bg[h+e]; xc[e] = bc[h+e];
    }
    for (int z = 0; z < nz; z++) {
        const unsigned short* Pz = P + (size_t)z * PPLANE;
        ushort8v vi = *(const ushort8v*)&Pz[base];
        ushort8v vf = *(const ushort8v*)&Pz[base + 2048];
        ushort8v vg = *(const ushort8v*)&Pz[base + 4096];
        ushort8v vc = *(const ushort8v*)&Pz[base + 6144];
        #pragma unroll
        for (int e = 0; e < 8; e++) {
            xi[e] += bf2f(vi[e]); xf[e] += bf2f(vf[e]);
            xg[e] += bf2f(vg[e]); xc[e] += bf2f(vc[e]);
        }
    }

    const float* po = states + BH;
    floatx4 pov[2];
    pov[0] = *(const floatx4*)&po[idx];
    pov[1] = *(const floatx4*)&po[idx + 4];

    floatx4 vcv[2], vsv[2];
    #pragma unroll
    for (int q = 0; q < 2; q++)
        #pragma unroll
        for (int j = 0; j < 4; j++) {
            int e = q*4 + j;
            float c = fsig(xf[e]) * pov[q][j] + fsig(xi[e]) * ftanh(xc[e]);
            vcv[q][j] = c;
            vsv[q][j] = fsig(xg[e]) * ftanh(c);
        }
    #pragma unroll
    for (int q = 0; q < 2; q++) {
        *(floatx4*)&out[idx + q*4]        = vcv[q];
        *(floatx4*)&out[BH + idx + q*4]   = vsv[q];
        *(floatx4*)&out[2*BH + idx + q*4] = vcv[q];
    }
}

extern "C" void kernel_launch(void* const* d_in, const int* in_sizes, int n_in,
                              void* d_out, int out_size, void* d_ws, size_t ws_size,
                              hipStream_t stream) {
    const float* inputs = (const float*)d_in[0];
    const float* states = (const float*)d_in[1];
    const float* Wi = (const float*)d_in[2];
    const float* Ui = (const float*)d_in[3];
    const float* bi = (const float*)d_in[4];
    const float* Wf = (const float*)d_in[5];
    const float* Uf = (const float*)d_in[6];
    const float* bf = (const float*)d_in[7];
    const float* Wg = (const float*)d_in[8];
    const float* Ug = (const float*)d_in[9];
    const float* bg = (const float*)d_in[10];
    const float* Wc = (const float*)d_in[11];
    const float* Uc = (const float*)d_in[12];
    const float* bc = (const float*)d_in[13];
    float* out = (float*)d_out;

    const size_t need = (WT_ELEMS + AB_ELEMS + 4 * PPLANE) * 2;   // 100 MiB
    if (ws_size >= need) {
        unsigned short* Wt = (unsigned short*)d_ws;
        unsigned short* Ab = Wt + WT_ELEMS;
        unsigned short* P  = Ab + AB_ELEMS;
        prep<<<9216, 256, 0, stream>>>(inputs, states, Wi, Ui, Wf, Uf,
                                       Wg, Ug, Wc, Uc, Wt, Ab);
        gemm_lds<<<dim3(64, 4, 4), 256, 0, stream>>>(Wt, Ab, P);
        combine_kernel<<<BH / (8 * 256), 256, 0, stream>>>(out, P, states,
                                                           bi, bf, bg, bc, 4);
    } else {
        unsigned short* P = (unsigned short*)d_ws;
        const int nz = (ws_size >= 4 * PLANE_BYTES) ? 4 : 2;
        const int KB = 4096 / nz;
        dim3 grid(64, 4, nz);
        gemm_tile<<<grid, 256, 0, stream>>>(inputs, states, Wi, Ui, Wf, Uf,
                                            Wg, Ug, Wc, Uc, P, KB);
        combine_kernel<<<BH / (8 * 256), 256, 0, stream>>>(out, P, states,
                                                           bi, bf, bg, bc, nz);
    }
}